// Round 2
// baseline (303.032 us; speedup 1.0000x reference)
//
#include <hip/hip_runtime.h>
#include <hip/hip_bf16.h>

// f32 variant: reference dtypes are float32; ints are int32.
typedef __bf16 bf16;
typedef __bf16 bf16x8 __attribute__((ext_vector_type(8)));
typedef float f32x4 __attribute__((ext_vector_type(4)));

#define NB 32
#define SS 2048
#define NN 65536   // NB*SS
#define DD 512
#define HH 4
#define HD 128
#define TT 24

// ---------------- ws layout (byte offsets) ----------------
// su  f32 [H][B][T]          @ 0        (12288 B)
// st  f32 [H][T][T]          @ 12288    (9216 B)
// b2  f32 [544]              @ 21504    (2176 B)
// k   f32 [H][T][HD]         @ 23680    (49152 B)
// v   f32 [H][T][HD]         @ 72832    (49152 B)
// qt  f32 [H][T][HD]         @ 121984   (49152 B)
// qu  f32 [H][B][HD]         @ 171136   (65536 B)
// w2t bf16 [544][96]         @ 236672   (104448 B)   total ~333 KB

// Kernel A1: k, v, qt, qu  (53248 dot-of-512 tasks).
// R1: split-K x4. Block = 64 outputs x 4 k-parts (256 thr). 832 blocks
// (was 208 -> 1 wave/SIMD, no latency hiding). Each thread does a 128-deep
// dot (2 chains of 64), partials combined through LDS.
__global__ __launch_bounds__(256) void prep1(
    const float* __restrict__ tslot, const float* __restrict__ smooth,
    const int* __restrict__ user_x, const float* __restrict__ upref,
    const float* __restrict__ Wq, const float* __restrict__ bq,
    const float* __restrict__ Wk, const float* __restrict__ bk,
    const float* __restrict__ Wv, const float* __restrict__ bv,
    float* __restrict__ ws_k, float* __restrict__ ws_v,
    float* __restrict__ ws_qt, float* __restrict__ ws_qu)
{
    __shared__ float part[4][64];
    __shared__ float* dstp[64];

    const int tid = threadIdx.x;
    const int kp = tid >> 6;           // k-part 0..3 (wave-uniform)
    const int eo = tid & 63;
    const int out_id = blockIdx.x * 64 + eo;   // < 53248; segment boundaries
                                               // (12288/24576/36864) are 64-aligned
    const float* x; const float* w; float bias; float* dst;
    if (out_id < 12288) {                    // k[h][t][e]
        int e = out_id & 127; int th = out_id >> 7; int t = th % TT; int h = th / TT;
        x = smooth + t * DD;
        w = Wk + (size_t)(h * DD) * HD + e;
        bias = bk[h * HD + e];
        dst = ws_k + out_id;
    } else if (out_id < 24576) {             // v[h][t][e]
        int idx = out_id - 12288;
        int e = idx & 127; int th = idx >> 7; int t = th % TT; int h = th / TT;
        x = smooth + t * DD;
        w = Wv + (size_t)(h * DD) * HD + e;
        bias = bv[h * HD + e];
        dst = ws_v + idx;
    } else if (out_id < 36864) {             // qt[h][t][e] (time half of Wq, +bq)
        int idx = out_id - 24576;
        int e = idx & 127; int th = idx >> 7; int t = th % TT; int h = th / TT;
        x = tslot + t * DD;
        w = Wq + (size_t)(h * 2 * DD + DD) * HD + e;
        bias = bq[h * HD + e];
        dst = ws_qt + idx;
    } else {                                 // qu[h][b][e] (user half of Wq)
        int idx = out_id - 36864;            // < 16384
        int e = idx & 127; int b = (idx >> 7) & 31; int h = idx >> 12;
        x = upref + (size_t)user_x[b] * DD;
        w = Wq + (size_t)(h * 2 * DD) * HD + e;
        bias = 0.f;
        dst = ws_qu + idx;
    }

    const int d0 = kp * 128;
    float a0 = 0.f, a1 = 0.f;
    #pragma unroll 8
    for (int d = 0; d < 64; ++d) {
        a0 += x[d0 + d]      * w[(size_t)(d0 + d)      * HD];
        a1 += x[d0 + 64 + d] * w[(size_t)(d0 + 64 + d) * HD];
    }
    part[kp][eo] = a0 + a1 + (kp == 0 ? bias : 0.f);
    if (kp == 0) dstp[eo] = dst;
    __syncthreads();
    if (tid < 64) {
        float s = part[0][tid] + part[1][tid] + part[2][tid] + part[3][tid];
        *dstp[tid] = s;
    }
}

// Kernel A2: su, st, W2T, b2 (needs A1 results).
// R1: w2t restructured. Old layout had lanes consecutive in i -> per-lane
// 512B-stride gathers of ws_v (~64 cache lines per load instr x 128 iters).
// New: one block per i (96 blocks); v-row staged in LDS (broadcast);
// lanes run along j -> Wu loads fully coalesced (1KB/wave contiguous).
// su/st/b2 unchanged, in blocks 96..119.
__global__ __launch_bounds__(256) void prep2(
    const float* __restrict__ ws_k, const float* __restrict__ ws_v,
    const float* __restrict__ ws_qt, const float* __restrict__ ws_qu,
    const float* __restrict__ Wu, const float* __restrict__ bu,
    const float* __restrict__ Wt, const float* __restrict__ bt,
    float* __restrict__ ws_su, float* __restrict__ ws_st,
    float* __restrict__ ws_b2, bf16* __restrict__ ws_w2t)
{
    const int tid = threadIdx.x;
    const int bx = blockIdx.x;

    if (bx < 96) {                           // w2t[j][i] for i = bx
        __shared__ float vrow[HD];
        const int i = bx;
        const int h = i / TT;
        if (tid < HD) vrow[tid] = ws_v[i * HD + tid];
        __syncthreads();

        const float* WuC = Wu + (size_t)(h * HD) * DD;   // [128][512] row-major
        const float* WtC = Wt + (size_t)(h * HD) * TT;   // [128][24]
        const int j0 = tid;          // < 512: Wu column
        const int j1 = tid + 256;    // < 512: Wu column
        float a0 = 0.f, a1 = 0.f;
        #pragma unroll 4
        for (int e = 0; e < HD; ++e) {
            float ve = vrow[e];
            a0 += ve * WuC[(size_t)e * DD + j0];
            a1 += ve * WuC[(size_t)e * DD + j1];
        }
        float a2 = 0.f;
        if (tid < TT) {              // j2 = tid+512 -> Wt column tid
            #pragma unroll 4
            for (int e = 0; e < HD; ++e)
                a2 += vrow[e] * WtC[(size_t)e * TT + tid];
        }
        ws_w2t[j0 * 96 + i] = (bf16)a0;
        ws_w2t[j1 * 96 + i] = (bf16)a1;
        if (tid < 32)                // cols 512..543 (536..543 are zero pad)
            ws_w2t[(tid + 512) * 96 + i] = (bf16)(tid < TT ? a2 : 0.f);
    } else {
        const int g = (bx - 96) * 256 + tid;
        if (g < 3072) {                      // su[h][b][t'] = qu . k
            int tp = g % TT; int hb = g / TT; // hb = h*32+b
            const float* q = ws_qu + hb * HD;
            int h = hb >> 5;
            const float* kk = ws_k + (h * TT + tp) * HD;
            float acc = 0.f;
            #pragma unroll 8
            for (int e = 0; e < HD; ++e) acc += q[e] * kk[e];
            ws_su[g] = acc;
        } else if (g < 5376) {               // st[h][t][t'] = qt . k
            int idx = g - 3072;
            int tp = idx % TT; int ht = idx / TT; int h = ht / TT;
            const float* q = ws_qt + ht * HD;
            const float* kk = ws_k + (h * TT + tp) * HD;
            float acc = 0.f;
            #pragma unroll 8
            for (int e = 0; e < HD; ++e) acc += q[e] * kk[e];
            ws_st[idx] = acc;
        } else if (g < 5920) {               // b2[j]
            int j = g - 5376;
            float val = (j < 512) ? bu[j] : ((j < 536) ? bt[j - 512] : 0.f);
            ws_b2[j] = val;
        }
    }
}

// Main fused kernel: 64 rows/block. Phase 1: attn[64][96] in LDS (bf16).
// Phase 2: [64x96] @ [96x544] via mfma_f32_16x16x32_bf16 with SWAPPED
// operands: D-tile = (W2T x attn^T), so lane's 4 acc regs are 4 consecutive
// OUTPUT COLUMNS of one row -> global_store_dwordx4 epilogue.
// R1: b derived from n0 (block-uniform; 64 | 2048 so the whole block shares
// one batch) + readfirstlane on the su offset -> su loads scalarize.
__global__ __launch_bounds__(256, 4) void fused_main(
    const int* __restrict__ hour_x, const int* __restrict__ hour_mask,
    const float* __restrict__ osc_u, const float* __restrict__ osc_v,
    const float* __restrict__ ws_su, const float* __restrict__ ws_st,
    const float* __restrict__ ws_b2, const bf16* __restrict__ ws_w2t,
    float* __restrict__ out_at, float* __restrict__ out_tl)
{
    __shared__ bf16 attn_lds[64][104];       // 96 used, stride 104 (16B-aligned rows)

    const int tid = threadIdx.x;
    const int h = tid >> 6;                  // wave-uniform head
    const int r = tid & 63;
    const int n0 = blockIdx.x * 64;
    const int n = n0 + r;
    const int b = n0 >> 11;                  // S = 2048; block-uniform
    const int hour = hour_x[n];

    const int su_off = __builtin_amdgcn_readfirstlane((h * NB + b) * TT);
    const float* su = ws_su + su_off;
    const float* st = ws_st + (h * TT + hour) * TT;
    const int*   mk = hour_mask + (size_t)n * TT;
    const float* up = osc_u + (size_t)(h * NN + n) * TT;
    const float* vp = osc_v + (size_t)(h * NN + n) * TT;

    float p[24];
    float ssum = 0.f;
    #pragma unroll
    for (int c = 0; c < 3; ++c) {            // 3 chunks x 8 timeslots
        float ub[8], vb[8], sub[8], stb[8];
        int mb[8];
        *(float4*)(ub)     = *(const float4*)(up + c * 8);
        *(float4*)(ub + 4) = *(const float4*)(up + c * 8 + 4);
        *(float4*)(vb)     = *(const float4*)(vp + c * 8);
        *(float4*)(vb + 4) = *(const float4*)(vp + c * 8 + 4);
        *(int4*)(mb)       = *(const int4*)(mk + c * 8);
        *(int4*)(mb + 4)   = *(const int4*)(mk + c * 8 + 4);
        *(float4*)(sub)     = *(const float4*)(su + c * 8);
        *(float4*)(sub + 4) = *(const float4*)(su + c * 8 + 4);
        *(float4*)(stb)     = *(const float4*)(st + c * 8);
        *(float4*)(stb + 4) = *(const float4*)(st + c * 8 + 4);
        #pragma unroll
        for (int j = 0; j < 8; ++j) {
            float s = (sub[j] + stb[j]) * 0.08838834764831845f;  // 1/sqrt(128)
            float du = 0.01f * ub[j] - 0.01f * vb[j];
            float g = __expf(-500.0f * s * s);
            float zz = du * g + fmaxf(s, 0.0f);
            zz = (mb[j] == 1) ? 0.0f : zz;   // masked: s=-inf => z=0 exactly
            float pp = __expf(zz);
            p[c * 8 + j] = pp;
            ssum += pp;
        }
        // fence: keep next chunk's loads below this point (caps live VGPRs)
        __builtin_amdgcn_sched_barrier(0);
    }
    float inv = 1.0f / ssum;

    // pack 24 bf16 and write as 3 x ds_write_b128
    bf16x8 pk[3];
    #pragma unroll
    for (int i = 0; i < 3; ++i)
        #pragma unroll
        for (int j = 0; j < 8; ++j) pk[i][j] = (bf16)(p[i * 8 + j] * inv);
    #pragma unroll
    for (int i = 0; i < 3; ++i)
        *(bf16x8*)(&attn_lds[r][h * TT + i * 8]) = pk[i];

    __syncthreads();

    // ---- phase 2: transposed-output MFMA GEMM ----
    const int w    = tid >> 6;
    const int lane = tid & 63;
    const int m16  = lane & 15;
    const int quad = lane >> 4;

    for (int ct = w; ct < 34; ct += 4) {
        const int c0 = ct * 16;
        const int cA = c0 + m16;             // W2T row (output column) for A-frag
        bf16x8 afr[3];
        #pragma unroll
        for (int kk = 0; kk < 3; ++kk)
            afr[kk] = *(const bf16x8*)(ws_w2t + cA * 96 + kk * 32 + quad * 8);
        const int cc0 = c0 + quad * 4;       // first of this lane's 4 output cols
        f32x4 bias4 = *(const f32x4*)(ws_b2 + cc0);

        #pragma unroll
        for (int rt = 0; rt < 4; ++rt) {
            f32x4 acc = {0.f, 0.f, 0.f, 0.f};
            #pragma unroll
            for (int kk = 0; kk < 3; ++kk) {
                bf16x8 bfr = *(const bf16x8*)(&attn_lds[rt * 16 + m16][kk * 32 + quad * 8]);
                acc = __builtin_amdgcn_mfma_f32_16x16x32_bf16(afr[kk], bfr, acc, 0, 0, 0);
            }
            const int row = n0 + rt * 16 + m16;   // D col (lane&15) = attn row
            f32x4 outv = acc + bias4;
            if (cc0 < 512) {
                __builtin_nontemporal_store(outv, (f32x4*)(out_at + (size_t)row * DD + cc0));
            } else if (cc0 < 536) {
                __builtin_nontemporal_store(outv, (f32x4*)(out_tl + (size_t)row * TT + (cc0 - 512)));
            }
        }
    }
}

extern "C" void kernel_launch(void* const* d_in, const int* in_sizes, int n_in,
                              void* d_out, int out_size, void* d_ws, size_t ws_size,
                              hipStream_t stream)
{
    const float* tslot  = (const float*)d_in[0];
    const float* smooth = (const float*)d_in[1];
    // d_in[2] user_embedded: unused by the reference
    const int*  user_x = (const int*)d_in[3];
    const int*  hour_x = (const int*)d_in[4];
    const int*  hour_mask = (const int*)d_in[5];
    const float* upref  = (const float*)d_in[6];
    const float* Wq = (const float*)d_in[7];
    const float* bq = (const float*)d_in[8];
    const float* Wk = (const float*)d_in[9];
    const float* bk = (const float*)d_in[10];
    const float* Wv = (const float*)d_in[11];
    const float* bv = (const float*)d_in[12];
    const float* Wu = (const float*)d_in[13];
    const float* bu = (const float*)d_in[14];
    const float* Wt = (const float*)d_in[15];
    const float* bt = (const float*)d_in[16];
    const float* osc_u = (const float*)d_in[17];
    const float* osc_v = (const float*)d_in[18];

    char* ws = (char*)d_ws;
    float* ws_su = (float*)(ws + 0);
    float* ws_st = (float*)(ws + 12288);
    float* ws_b2 = (float*)(ws + 21504);
    float* ws_k  = (float*)(ws + 23680);
    float* ws_v  = (float*)(ws + 72832);
    float* ws_qt = (float*)(ws + 121984);
    float* ws_qu = (float*)(ws + 171136);
    bf16*  ws_w2t = (bf16*)(ws + 236672);

    float* out_at = (float*)d_out;
    float* out_tl = out_at + (size_t)NN * DD;

    prep1<<<832, 256, 0, stream>>>(tslot, smooth, user_x, upref, Wq, bq, Wk, bk,
                                   Wv, bv, ws_k, ws_v, ws_qt, ws_qu);
    prep2<<<120, 256, 0, stream>>>(ws_k, ws_v, ws_qt, ws_qu, Wu, bu, Wt, bt,
                                   ws_su, ws_st, ws_b2, ws_w2t);
    fused_main<<<NN / 64, 256, 0, stream>>>(hour_x, hour_mask, osc_u, osc_v,
                                            ws_su, ws_st, ws_b2, ws_w2t,
                                            out_at, out_tl);
}

// Round 3
// 302.581 us; speedup vs baseline: 1.0015x; 1.0015x over previous
//
#include <hip/hip_runtime.h>
#include <hip/hip_bf16.h>

// f32 variant: reference dtypes are float32; ints are int32.
typedef __bf16 bf16;
typedef __bf16 bf16x2 __attribute__((ext_vector_type(2)));
typedef __bf16 bf16x8 __attribute__((ext_vector_type(8)));
typedef float f32x4 __attribute__((ext_vector_type(4)));

#define NB 32
#define SS 2048
#define NN 65536   // NB*SS
#define DD 512
#define HH 4
#define HD 128
#define TT 24

// ---------------- ws layout (byte offsets) ----------------
// su  f32 [H][B][T]          @ 0        (12288 B)
// st  f32 [H][T][T]          @ 12288    (9216 B)
// b2  f32 [544]              @ 21504    (2176 B)
// k   f32 [H][T][HD]         @ 23680    (49152 B)
// v   f32 [H][T][HD]         @ 72832    (49152 B)
// qt  f32 [H][T][HD]         @ 121984   (49152 B)
// qu  f32 [H][B][HD]         @ 171136   (65536 B)
// w2t bf16 [544][96]         @ 236672   (104448 B)   total ~333 KB

// Kernel A1: k, v, qt, qu  (53248 dot-of-512 tasks).
// Split-K x4. Block = 64 outputs x 4 k-parts (256 thr). 832 blocks.
__global__ __launch_bounds__(256) void prep1(
    const float* __restrict__ tslot, const float* __restrict__ smooth,
    const int* __restrict__ user_x, const float* __restrict__ upref,
    const float* __restrict__ Wq, const float* __restrict__ bq,
    const float* __restrict__ Wk, const float* __restrict__ bk,
    const float* __restrict__ Wv, const float* __restrict__ bv,
    float* __restrict__ ws_k, float* __restrict__ ws_v,
    float* __restrict__ ws_qt, float* __restrict__ ws_qu)
{
    __shared__ float part[4][64];
    __shared__ float* dstp[64];

    const int tid = threadIdx.x;
    const int kp = tid >> 6;           // k-part 0..3 (wave-uniform)
    const int eo = tid & 63;
    const int out_id = blockIdx.x * 64 + eo;   // < 53248; segment boundaries
                                               // (12288/24576/36864) are 64-aligned
    const float* x; const float* w; float bias; float* dst;
    if (out_id < 12288) {                    // k[h][t][e]
        int e = out_id & 127; int th = out_id >> 7; int t = th % TT; int h = th / TT;
        x = smooth + t * DD;
        w = Wk + (size_t)(h * DD) * HD + e;
        bias = bk[h * HD + e];
        dst = ws_k + out_id;
    } else if (out_id < 24576) {             // v[h][t][e]
        int idx = out_id - 12288;
        int e = idx & 127; int th = idx >> 7; int t = th % TT; int h = th / TT;
        x = smooth + t * DD;
        w = Wv + (size_t)(h * DD) * HD + e;
        bias = bv[h * HD + e];
        dst = ws_v + idx;
    } else if (out_id < 36864) {             // qt[h][t][e] (time half of Wq, +bq)
        int idx = out_id - 24576;
        int e = idx & 127; int th = idx >> 7; int t = th % TT; int h = th / TT;
        x = tslot + t * DD;
        w = Wq + (size_t)(h * 2 * DD + DD) * HD + e;
        bias = bq[h * HD + e];
        dst = ws_qt + idx;
    } else {                                 // qu[h][b][e] (user half of Wq)
        int idx = out_id - 36864;            // < 16384
        int e = idx & 127; int b = (idx >> 7) & 31; int h = idx >> 12;
        x = upref + (size_t)user_x[b] * DD;
        w = Wq + (size_t)(h * 2 * DD) * HD + e;
        bias = 0.f;
        dst = ws_qu + idx;
    }

    const int d0 = kp * 128;
    float a0 = 0.f, a1 = 0.f;
    #pragma unroll 8
    for (int d = 0; d < 64; ++d) {
        a0 += x[d0 + d]      * w[(size_t)(d0 + d)      * HD];
        a1 += x[d0 + 64 + d] * w[(size_t)(d0 + 64 + d) * HD];
    }
    part[kp][eo] = a0 + a1 + (kp == 0 ? bias : 0.f);
    if (kp == 0) dstp[eo] = dst;
    __syncthreads();
    if (tid < 64) {
        float s = part[0][tid] + part[1][tid] + part[2][tid] + part[3][tid];
        *dstp[tid] = s;
    }
}

// Kernel A2: su, st, W2T, b2 (needs A1 results).
// w2t: one block per i (96 blocks); v-row staged in LDS (broadcast);
// lanes run along j -> Wu loads fully coalesced. su/st/b2 in blocks 96..119.
__global__ __launch_bounds__(256) void prep2(
    const float* __restrict__ ws_k, const float* __restrict__ ws_v,
    const float* __restrict__ ws_qt, const float* __restrict__ ws_qu,
    const float* __restrict__ Wu, const float* __restrict__ bu,
    const float* __restrict__ Wt, const float* __restrict__ bt,
    float* __restrict__ ws_su, float* __restrict__ ws_st,
    float* __restrict__ ws_b2, bf16* __restrict__ ws_w2t)
{
    const int tid = threadIdx.x;
    const int bx = blockIdx.x;

    if (bx < 96) {                           // w2t[j][i] for i = bx
        __shared__ float vrow[HD];
        const int i = bx;
        const int h = i / TT;
        if (tid < HD) vrow[tid] = ws_v[i * HD + tid];
        __syncthreads();

        const float* WuC = Wu + (size_t)(h * HD) * DD;   // [128][512] row-major
        const float* WtC = Wt + (size_t)(h * HD) * TT;   // [128][24]
        const int j0 = tid;          // < 512: Wu column
        const int j1 = tid + 256;    // < 512: Wu column
        float a0 = 0.f, a1 = 0.f;
        #pragma unroll 4
        for (int e = 0; e < HD; ++e) {
            float ve = vrow[e];
            a0 += ve * WuC[(size_t)e * DD + j0];
            a1 += ve * WuC[(size_t)e * DD + j1];
        }
        float a2 = 0.f;
        if (tid < TT) {              // j2 = tid+512 -> Wt column tid
            #pragma unroll 4
            for (int e = 0; e < HD; ++e)
                a2 += vrow[e] * WtC[(size_t)e * TT + tid];
        }
        ws_w2t[j0 * 96 + i] = (bf16)a0;
        ws_w2t[j1 * 96 + i] = (bf16)a1;
        if (tid < 32)                // cols 512..543 (536..543 are zero pad)
            ws_w2t[(tid + 512) * 96 + i] = (bf16)(tid < TT ? a2 : 0.f);
    } else {
        const int g = (bx - 96) * 256 + tid;
        if (g < 3072) {                      // su[h][b][t'] = qu . k
            int tp = g % TT; int hb = g / TT; // hb = h*32+b
            const float* q = ws_qu + hb * HD;
            int h = hb >> 5;
            const float* kk = ws_k + (h * TT + tp) * HD;
            float acc = 0.f;
            #pragma unroll 8
            for (int e = 0; e < HD; ++e) acc += q[e] * kk[e];
            ws_su[g] = acc;
        } else if (g < 5376) {               // st[h][t][t'] = qt . k
            int idx = g - 3072;
            int tp = idx % TT; int ht = idx / TT; int h = ht / TT;
            const float* q = ws_qt + ht * HD;
            const float* kk = ws_k + (h * TT + tp) * HD;
            float acc = 0.f;
            #pragma unroll 8
            for (int e = 0; e < HD; ++e) acc += q[e] * kk[e];
            ws_st[idx] = acc;
        } else if (g < 5920) {               // b2[j]
            int j = g - 5376;
            float val = (j < 512) ? bu[j] : ((j < 536) ? bt[j - 512] : 0.f);
            ws_b2[j] = val;
        }
    }
}

// Main fused kernel: 64 rows/block.
// R2 change (phase 1): thread = (row, slot-group) instead of (row, head).
// 256 thr = 64 rows x 4 quarter-rows (6 slots), looping h=0..3. Old mapping
// gave every staging load a 96B lane stride -> ~64 cache-line probes per
// wave instruction x 30 instructions (TA/issue-bound at 4 blocks/CU). New
// mapping: consecutive lanes read consecutive 24B -> dense ~512B/wave
// dwordx2 loads (8 lines/instr). hour_mask is head-independent -> loaded
// once (was 4x = 19MB extra). Softmax denom via 2-step __shfl_xor over the
// 4-lane group. Phase 2 (MFMA + transposed-output stores) unchanged.
__global__ __launch_bounds__(256, 4) void fused_main(
    const int* __restrict__ hour_x, const int* __restrict__ hour_mask,
    const float* __restrict__ osc_u, const float* __restrict__ osc_v,
    const float* __restrict__ ws_su, const float* __restrict__ ws_st,
    const float* __restrict__ ws_b2, const bf16* __restrict__ ws_w2t,
    float* __restrict__ out_at, float* __restrict__ out_tl)
{
    __shared__ bf16 attn_lds[64][104];       // 96 used, stride 104 (16B-aligned rows)

    const int tid = threadIdx.x;
    const int r  = tid >> 2;                 // row 0..63
    const int q6 = (tid & 3) * 6;            // slot-group offset 0/6/12/18
    const int n0 = blockIdx.x * 64;
    const int n  = n0 + r;
    const int b  = n0 >> 11;                 // S = 2048; block-uniform
    const int hour = hour_x[n];              // 4 lanes share -> broadcast

    // mask slots: head-independent, load once
    int mb[6];
    {
        const int* mk = hour_mask + (size_t)n * TT + q6;
        *(int2*)(mb)     = *(const int2*)(mk);
        *(int2*)(mb + 2) = *(const int2*)(mk + 2);
        *(int2*)(mb + 4) = *(const int2*)(mk + 4);
    }

    #pragma unroll
    for (int h = 0; h < HH; ++h) {
        const float* up  = osc_u + ((size_t)h * NN + n) * TT + q6;
        const float* vp  = osc_v + ((size_t)h * NN + n) * TT + q6;
        const float* sup = ws_su + (h * NB + b) * TT + q6;   // wave-broadcast
        const float* stp = ws_st + (h * TT + hour) * TT + q6; // L1-resident 9KB

        float ub[6], vb[6], sb[6], tb[6];
        *(float2*)(ub)     = *(const float2*)(up);
        *(float2*)(ub + 2) = *(const float2*)(up + 2);
        *(float2*)(ub + 4) = *(const float2*)(up + 4);
        *(float2*)(vb)     = *(const float2*)(vp);
        *(float2*)(vb + 2) = *(const float2*)(vp + 2);
        *(float2*)(vb + 4) = *(const float2*)(vp + 4);
        *(float2*)(sb)     = *(const float2*)(sup);
        *(float2*)(sb + 2) = *(const float2*)(sup + 2);
        *(float2*)(sb + 4) = *(const float2*)(sup + 4);
        *(float2*)(tb)     = *(const float2*)(stp);
        *(float2*)(tb + 2) = *(const float2*)(stp + 2);
        *(float2*)(tb + 4) = *(const float2*)(stp + 4);

        float p6[6];
        float psum = 0.f;
        #pragma unroll
        for (int j = 0; j < 6; ++j) {
            float s = (sb[j] + tb[j]) * 0.08838834764831845f;  // 1/sqrt(128)
            float du = 0.01f * ub[j] - 0.01f * vb[j];
            float g = __expf(-500.0f * s * s);
            float zz = du * g + fmaxf(s, 0.0f);
            zz = (mb[j] == 1) ? 0.0f : zz;   // masked: s=-inf => z=0 exactly
            float pp = __expf(zz);
            p6[j] = pp;
            psum += pp;
        }
        // sum over the 4 slot-groups of this row (lanes l^1, l^2 share row)
        psum += __shfl_xor(psum, 1);
        psum += __shfl_xor(psum, 2);
        float inv = 1.0f / psum;

        #pragma unroll
        for (int k2 = 0; k2 < 3; ++k2) {
            bf16x2 w2;
            w2[0] = (bf16)(p6[2 * k2]     * inv);
            w2[1] = (bf16)(p6[2 * k2 + 1] * inv);
            *(bf16x2*)(&attn_lds[r][h * TT + q6 + 2 * k2]) = w2;
        }
    }

    __syncthreads();

    // ---- phase 2: transposed-output MFMA GEMM ----
    const int w    = tid >> 6;
    const int lane = tid & 63;
    const int m16  = lane & 15;
    const int quad = lane >> 4;

    for (int ct = w; ct < 34; ct += 4) {
        const int c0 = ct * 16;
        const int cA = c0 + m16;             // W2T row (output column) for A-frag
        bf16x8 afr[3];
        #pragma unroll
        for (int kk = 0; kk < 3; ++kk)
            afr[kk] = *(const bf16x8*)(ws_w2t + cA * 96 + kk * 32 + quad * 8);
        const int cc0 = c0 + quad * 4;       // first of this lane's 4 output cols
        f32x4 bias4 = *(const f32x4*)(ws_b2 + cc0);

        #pragma unroll
        for (int rt = 0; rt < 4; ++rt) {
            f32x4 acc = {0.f, 0.f, 0.f, 0.f};
            #pragma unroll
            for (int kk = 0; kk < 3; ++kk) {
                bf16x8 bfr = *(const bf16x8*)(&attn_lds[rt * 16 + m16][kk * 32 + quad * 8]);
                acc = __builtin_amdgcn_mfma_f32_16x16x32_bf16(afr[kk], bfr, acc, 0, 0, 0);
            }
            const int row = n0 + rt * 16 + m16;   // D col (lane&15) = attn row
            f32x4 outv = acc + bias4;
            if (cc0 < 512) {
                __builtin_nontemporal_store(outv, (f32x4*)(out_at + (size_t)row * DD + cc0));
            } else if (cc0 < 536) {
                __builtin_nontemporal_store(outv, (f32x4*)(out_tl + (size_t)row * TT + (cc0 - 512)));
            }
        }
    }
}

extern "C" void kernel_launch(void* const* d_in, const int* in_sizes, int n_in,
                              void* d_out, int out_size, void* d_ws, size_t ws_size,
                              hipStream_t stream)
{
    const float* tslot  = (const float*)d_in[0];
    const float* smooth = (const float*)d_in[1];
    // d_in[2] user_embedded: unused by the reference
    const int*  user_x = (const int*)d_in[3];
    const int*  hour_x = (const int*)d_in[4];
    const int*  hour_mask = (const int*)d_in[5];
    const float* upref  = (const float*)d_in[6];
    const float* Wq = (const float*)d_in[7];
    const float* bq = (const float*)d_in[8];
    const float* Wk = (const float*)d_in[9];
    const float* bk = (const float*)d_in[10];
    const float* Wv = (const float*)d_in[11];
    const float* bv = (const float*)d_in[12];
    const float* Wu = (const float*)d_in[13];
    const float* bu = (const float*)d_in[14];
    const float* Wt = (const float*)d_in[15];
    const float* bt = (const float*)d_in[16];
    const float* osc_u = (const float*)d_in[17];
    const float* osc_v = (const float*)d_in[18];

    char* ws = (char*)d_ws;
    float* ws_su = (float*)(ws + 0);
    float* ws_st = (float*)(ws + 12288);
    float* ws_b2 = (float*)(ws + 21504);
    float* ws_k  = (float*)(ws + 23680);
    float* ws_v  = (float*)(ws + 72832);
    float* ws_qt = (float*)(ws + 121984);
    float* ws_qu = (float*)(ws + 171136);
    bf16*  ws_w2t = (bf16*)(ws + 236672);

    float* out_at = (float*)d_out;
    float* out_tl = out_at + (size_t)NN * DD;

    prep1<<<832, 256, 0, stream>>>(tslot, smooth, user_x, upref, Wq, bq, Wk, bk,
                                   Wv, bv, ws_k, ws_v, ws_qt, ws_qu);
    prep2<<<120, 256, 0, stream>>>(ws_k, ws_v, ws_qt, ws_qu, Wu, bu, Wt, bt,
                                   ws_su, ws_st, ws_b2, ws_w2t);
    fused_main<<<NN / 64, 256, 0, stream>>>(hour_x, hour_mask, osc_u, osc_v,
                                            ws_su, ws_st, ws_b2, ws_w2t,
                                            out_at, out_tl);
}

// Round 4
// 299.842 us; speedup vs baseline: 1.0106x; 1.0091x over previous
//
#include <hip/hip_runtime.h>
#include <hip/hip_bf16.h>

// f32 variant: reference dtypes are float32; ints are int32.
typedef __bf16 bf16;
typedef __bf16 bf16x2 __attribute__((ext_vector_type(2)));
typedef __bf16 bf16x8 __attribute__((ext_vector_type(8)));
typedef float f32x4 __attribute__((ext_vector_type(4)));

#define NB 32
#define SS 2048
#define NN 65536   // NB*SS
#define DD 512
#define HH 4
#define HD 128
#define TT 24

// ---------------- ws layout (byte offsets) ----------------
// su  f32 [H][B][T]          @ 0        (12288 B)
// st  f32 [H][T][T]          @ 12288    (9216 B)
// b2  f32 [544]              @ 21504    (2176 B)
// k   f32 [H][T][HD]         @ 23680    (49152 B)
// v   f32 [H][T][HD]         @ 72832    (49152 B)
// qt  f32 [H][T][HD]         @ 121984   (49152 B)
// qu  f32 [H][B][HD]         @ 171136   (65536 B)
// w2p bf16 [34][3][64][8]    @ 236672   (104448 B)  MFMA-fragment order
//   element (output col j, k idx i): ct=j>>4, m16=j&15, kk=i>>5,
//   quad=(i>>3)&3, e=i&7 -> off = ((ct*3+kk)*64 + quad*16 + m16)*8 + e

// Kernel A1: k, v, qt, qu  (53248 dot-of-512 tasks).
// Split-K x4. Block = 64 outputs x 4 k-parts (256 thr). 832 blocks.
__global__ __launch_bounds__(256) void prep1(
    const float* __restrict__ tslot, const float* __restrict__ smooth,
    const int* __restrict__ user_x, const float* __restrict__ upref,
    const float* __restrict__ Wq, const float* __restrict__ bq,
    const float* __restrict__ Wk, const float* __restrict__ bk,
    const float* __restrict__ Wv, const float* __restrict__ bv,
    float* __restrict__ ws_k, float* __restrict__ ws_v,
    float* __restrict__ ws_qt, float* __restrict__ ws_qu)
{
    __shared__ float part[4][64];
    __shared__ float* dstp[64];

    const int tid = threadIdx.x;
    const int kp = tid >> 6;           // k-part 0..3 (wave-uniform)
    const int eo = tid & 63;
    const int out_id = blockIdx.x * 64 + eo;   // < 53248; segment boundaries
                                               // (12288/24576/36864) are 64-aligned
    const float* x; const float* w; float bias; float* dst;
    if (out_id < 12288) {                    // k[h][t][e]
        int e = out_id & 127; int th = out_id >> 7; int t = th % TT; int h = th / TT;
        x = smooth + t * DD;
        w = Wk + (size_t)(h * DD) * HD + e;
        bias = bk[h * HD + e];
        dst = ws_k + out_id;
    } else if (out_id < 24576) {             // v[h][t][e]
        int idx = out_id - 12288;
        int e = idx & 127; int th = idx >> 7; int t = th % TT; int h = th / TT;
        x = smooth + t * DD;
        w = Wv + (size_t)(h * DD) * HD + e;
        bias = bv[h * HD + e];
        dst = ws_v + idx;
    } else if (out_id < 36864) {             // qt[h][t][e] (time half of Wq, +bq)
        int idx = out_id - 24576;
        int e = idx & 127; int th = idx >> 7; int t = th % TT; int h = th / TT;
        x = tslot + t * DD;
        w = Wq + (size_t)(h * 2 * DD + DD) * HD + e;
        bias = bq[h * HD + e];
        dst = ws_qt + idx;
    } else {                                 // qu[h][b][e] (user half of Wq)
        int idx = out_id - 36864;            // < 16384
        int e = idx & 127; int b = (idx >> 7) & 31; int h = idx >> 12;
        x = upref + (size_t)user_x[b] * DD;
        w = Wq + (size_t)(h * 2 * DD) * HD + e;
        bias = 0.f;
        dst = ws_qu + idx;
    }

    const int d0 = kp * 128;
    float a0 = 0.f, a1 = 0.f;
    #pragma unroll 8
    for (int d = 0; d < 64; ++d) {
        a0 += x[d0 + d]      * w[(size_t)(d0 + d)      * HD];
        a1 += x[d0 + 64 + d] * w[(size_t)(d0 + 64 + d) * HD];
    }
    part[kp][eo] = a0 + a1 + (kp == 0 ? bias : 0.f);
    if (kp == 0) dstp[eo] = dst;
    __syncthreads();
    if (tid < 64) {
        float s = part[0][tid] + part[1][tid] + part[2][tid] + part[3][tid];
        *dstp[tid] = s;
    }
}

// Kernel A2: su, st, W2P, b2 (needs A1 results).
// w2p: one block per k-index i (96 blocks); v-row staged in LDS (broadcast);
// lanes run along j -> Wu loads fully coalesced. Stores go to the
// MFMA-fragment-ordered w2p layout. su/st/b2 in blocks 96..119.
__global__ __launch_bounds__(256) void prep2(
    const float* __restrict__ ws_k, const float* __restrict__ ws_v,
    const float* __restrict__ ws_qt, const float* __restrict__ ws_qu,
    const float* __restrict__ Wu, const float* __restrict__ bu,
    const float* __restrict__ Wt, const float* __restrict__ bt,
    float* __restrict__ ws_su, float* __restrict__ ws_st,
    float* __restrict__ ws_b2, bf16* __restrict__ ws_w2p)
{
    const int tid = threadIdx.x;
    const int bx = blockIdx.x;

    if (bx < 96) {                           // w2p entries for k-index i = bx
        __shared__ float vrow[HD];
        const int i = bx;
        const int h = i / TT;
        if (tid < HD) vrow[tid] = ws_v[i * HD + tid];
        __syncthreads();

        // fragment coords from i (block-uniform)
        const int kk  = i >> 5;
        const int qd  = (i >> 3) & 3;
        const int e   = i & 7;

        const float* WuC = Wu + (size_t)(h * HD) * DD;   // [128][512] row-major
        const float* WtC = Wt + (size_t)(h * HD) * TT;   // [128][24]
        const int j0 = tid;          // < 512: Wu column
        const int j1 = tid + 256;    // < 512: Wu column
        float a0 = 0.f, a1 = 0.f;
        #pragma unroll 4
        for (int ee = 0; ee < HD; ++ee) {
            float ve = vrow[ee];
            a0 += ve * WuC[(size_t)ee * DD + j0];
            a1 += ve * WuC[(size_t)ee * DD + j1];
        }
        float a2 = 0.f;
        if (tid < TT) {              // j2 = tid+512 -> Wt column tid
            #pragma unroll 4
            for (int ee = 0; ee < HD; ++ee)
                a2 += vrow[ee] * WtC[(size_t)ee * TT + tid];
        }
        // store (j, i) at ((ct*3+kk)*64 + qd*16 + m16)*8 + e
        {
            int ct = j0 >> 4, m16 = j0 & 15;
            ws_w2p[(((ct * 3 + kk) * 64) + qd * 16 + m16) * 8 + e] = (bf16)a0;
        }
        {
            int ct = j1 >> 4, m16 = j1 & 15;
            ws_w2p[(((ct * 3 + kk) * 64) + qd * 16 + m16) * 8 + e] = (bf16)a1;
        }
        if (tid < 32) {              // cols 512..543 (536..543 are zero pad)
            int j = tid + 512;
            int ct = j >> 4, m16 = j & 15;
            ws_w2p[(((ct * 3 + kk) * 64) + qd * 16 + m16) * 8 + e] =
                (bf16)(tid < TT ? a2 : 0.f);
        }
    } else {
        const int g = (bx - 96) * 256 + tid;
        if (g < 3072) {                      // su[h][b][t'] = qu . k
            int tp = g % TT; int hb = g / TT; // hb = h*32+b
            const float* q = ws_qu + hb * HD;
            int h = hb >> 5;
            const float* kk = ws_k + (h * TT + tp) * HD;
            float acc = 0.f;
            #pragma unroll 8
            for (int e = 0; e < HD; ++e) acc += q[e] * kk[e];
            ws_su[g] = acc;
        } else if (g < 5376) {               // st[h][t][t'] = qt . k
            int idx = g - 3072;
            int tp = idx % TT; int ht = idx / TT; int h = ht / TT;
            const float* q = ws_qt + ht * HD;
            const float* kk = ws_k + (h * TT + tp) * HD;
            float acc = 0.f;
            #pragma unroll 8
            for (int e = 0; e < HD; ++e) acc += q[e] * kk[e];
            ws_st[idx] = acc;
        } else if (g < 5920) {               // b2[j]
            int j = g - 5376;
            float val = (j < 512) ? bu[j] : ((j < 536) ? bt[j - 512] : 0.f);
            ws_b2[j] = val;
        }
    }
}

// Main fused kernel: 64 rows/block.
// Phase 1 (R2): thread = (row, slot-group); dense ~512B/wave loads; mask
// loaded once; softmax denom via 2-step __shfl_xor over 4-lane groups.
// Phase 2 (R3): fragment loads from the w2p layout are base + lane*16B ->
// one fully-coalesced 1KB wave load per (ct,kk) instead of a 64-line
// gather at 192B lane stride (was 27 TA-serialized gathers per wave).
// MFMA math, LDS reads, store epilogue unchanged.
__global__ __launch_bounds__(256, 4) void fused_main(
    const int* __restrict__ hour_x, const int* __restrict__ hour_mask,
    const float* __restrict__ osc_u, const float* __restrict__ osc_v,
    const float* __restrict__ ws_su, const float* __restrict__ ws_st,
    const float* __restrict__ ws_b2, const bf16* __restrict__ ws_w2p,
    float* __restrict__ out_at, float* __restrict__ out_tl)
{
    __shared__ bf16 attn_lds[64][104];       // 96 used, stride 104 (16B-aligned rows)

    const int tid = threadIdx.x;
    const int r  = tid >> 2;                 // row 0..63
    const int q6 = (tid & 3) * 6;            // slot-group offset 0/6/12/18
    const int n0 = blockIdx.x * 64;
    const int n  = n0 + r;
    const int b  = n0 >> 11;                 // S = 2048; block-uniform
    const int hour = hour_x[n];              // 4 lanes share -> broadcast

    // mask slots: head-independent, load once
    int mb[6];
    {
        const int* mk = hour_mask + (size_t)n * TT + q6;
        *(int2*)(mb)     = *(const int2*)(mk);
        *(int2*)(mb + 2) = *(const int2*)(mk + 2);
        *(int2*)(mb + 4) = *(const int2*)(mk + 4);
    }

    #pragma unroll
    for (int h = 0; h < HH; ++h) {
        const float* up  = osc_u + ((size_t)h * NN + n) * TT + q6;
        const float* vp  = osc_v + ((size_t)h * NN + n) * TT + q6;
        const float* sup = ws_su + (h * NB + b) * TT + q6;   // wave-broadcast
        const float* stp = ws_st + (h * TT + hour) * TT + q6; // L1-resident 9KB

        float ub[6], vb[6], sb[6], tb[6];
        *(float2*)(ub)     = *(const float2*)(up);
        *(float2*)(ub + 2) = *(const float2*)(up + 2);
        *(float2*)(ub + 4) = *(const float2*)(up + 4);
        *(float2*)(vb)     = *(const float2*)(vp);
        *(float2*)(vb + 2) = *(const float2*)(vp + 2);
        *(float2*)(vb + 4) = *(const float2*)(vp + 4);
        *(float2*)(sb)     = *(const float2*)(sup);
        *(float2*)(sb + 2) = *(const float2*)(sup + 2);
        *(float2*)(sb + 4) = *(const float2*)(sup + 4);
        *(float2*)(tb)     = *(const float2*)(stp);
        *(float2*)(tb + 2) = *(const float2*)(stp + 2);
        *(float2*)(tb + 4) = *(const float2*)(stp + 4);

        float p6[6];
        float psum = 0.f;
        #pragma unroll
        for (int j = 0; j < 6; ++j) {
            float s = (sb[j] + tb[j]) * 0.08838834764831845f;  // 1/sqrt(128)
            float du = 0.01f * ub[j] - 0.01f * vb[j];
            float g = __expf(-500.0f * s * s);
            float zz = du * g + fmaxf(s, 0.0f);
            zz = (mb[j] == 1) ? 0.0f : zz;   // masked: s=-inf => z=0 exactly
            float pp = __expf(zz);
            p6[j] = pp;
            psum += pp;
        }
        // sum over the 4 slot-groups of this row (lanes l^1, l^2 share row)
        psum += __shfl_xor(psum, 1);
        psum += __shfl_xor(psum, 2);
        float inv = 1.0f / psum;

        #pragma unroll
        for (int k2 = 0; k2 < 3; ++k2) {
            bf16x2 w2;
            w2[0] = (bf16)(p6[2 * k2]     * inv);
            w2[1] = (bf16)(p6[2 * k2 + 1] * inv);
            *(bf16x2*)(&attn_lds[r][h * TT + q6 + 2 * k2]) = w2;
        }
    }

    __syncthreads();

    // ---- phase 2: transposed-output MFMA GEMM ----
    const int w    = tid >> 6;
    const int lane = tid & 63;
    const int m16  = lane & 15;
    const int quad = lane >> 4;

    for (int ct = w; ct < 34; ct += 4) {
        const int c0 = ct * 16;
        bf16x8 afr[3];
        #pragma unroll
        for (int kk = 0; kk < 3; ++kk)
            afr[kk] = *(const bf16x8*)(ws_w2p + ((size_t)(ct * 3 + kk) * 64 + lane) * 8);
        const int cc0 = c0 + quad * 4;       // first of this lane's 4 output cols
        f32x4 bias4 = *(const f32x4*)(ws_b2 + cc0);

        #pragma unroll
        for (int rt = 0; rt < 4; ++rt) {
            f32x4 acc = {0.f, 0.f, 0.f, 0.f};
            #pragma unroll
            for (int kk = 0; kk < 3; ++kk) {
                bf16x8 bfr = *(const bf16x8*)(&attn_lds[rt * 16 + m16][kk * 32 + quad * 8]);
                acc = __builtin_amdgcn_mfma_f32_16x16x32_bf16(afr[kk], bfr, acc, 0, 0, 0);
            }
            const int row = n0 + rt * 16 + m16;   // D col (lane&15) = attn row
            f32x4 outv = acc + bias4;
            if (cc0 < 512) {
                __builtin_nontemporal_store(outv, (f32x4*)(out_at + (size_t)row * DD + cc0));
            } else if (cc0 < 536) {
                __builtin_nontemporal_store(outv, (f32x4*)(out_tl + (size_t)row * TT + (cc0 - 512)));
            }
        }
    }
}

extern "C" void kernel_launch(void* const* d_in, const int* in_sizes, int n_in,
                              void* d_out, int out_size, void* d_ws, size_t ws_size,
                              hipStream_t stream)
{
    const float* tslot  = (const float*)d_in[0];
    const float* smooth = (const float*)d_in[1];
    // d_in[2] user_embedded: unused by the reference
    const int*  user_x = (const int*)d_in[3];
    const int*  hour_x = (const int*)d_in[4];
    const int*  hour_mask = (const int*)d_in[5];
    const float* upref  = (const float*)d_in[6];
    const float* Wq = (const float*)d_in[7];
    const float* bq = (const float*)d_in[8];
    const float* Wk = (const float*)d_in[9];
    const float* bk = (const float*)d_in[10];
    const float* Wv = (const float*)d_in[11];
    const float* bv = (const float*)d_in[12];
    const float* Wu = (const float*)d_in[13];
    const float* bu = (const float*)d_in[14];
    const float* Wt = (const float*)d_in[15];
    const float* bt = (const float*)d_in[16];
    const float* osc_u = (const float*)d_in[17];
    const float* osc_v = (const float*)d_in[18];

    char* ws = (char*)d_ws;
    float* ws_su = (float*)(ws + 0);
    float* ws_st = (float*)(ws + 12288);
    float* ws_b2 = (float*)(ws + 21504);
    float* ws_k  = (float*)(ws + 23680);
    float* ws_v  = (float*)(ws + 72832);
    float* ws_qt = (float*)(ws + 121984);
    float* ws_qu = (float*)(ws + 171136);
    bf16*  ws_w2p = (bf16*)(ws + 236672);

    float* out_at = (float*)d_out;
    float* out_tl = out_at + (size_t)NN * DD;

    prep1<<<832, 256, 0, stream>>>(tslot, smooth, user_x, upref, Wq, bq, Wk, bk,
                                   Wv, bv, ws_k, ws_v, ws_qt, ws_qu);
    prep2<<<120, 256, 0, stream>>>(ws_k, ws_v, ws_qt, ws_qu, Wu, bu, Wt, bt,
                                   ws_su, ws_st, ws_b2, ws_w2p);
    fused_main<<<NN / 64, 256, 0, stream>>>(hour_x, hour_mask, osc_u, osc_v,
                                            ws_su, ws_st, ws_b2, ws_w2p,
                                            out_at, out_tl);
}